// Round 1
// baseline (104.301 us; speedup 1.0000x reference)
//
#include <hip/hip_runtime.h>
#include <math.h>

#define BB 524288
#define CC 10
#define TT 25

__global__ void init_out_kernel(float* out) {
    // output = -mean_b(M_b + log S_b - log T) = logT - (1/B) * sum_b(M_b + log S_b)
    *out = logf((float)TT);
}

__global__ __launch_bounds__(256) void mc_nll_kernel(
    const float* __restrict__ mu,
    const float* __restrict__ ls2,
    const int*   __restrict__ y,
    const float* __restrict__ eps,
    float* __restrict__ out)
{
    const int b = blockIdx.x * blockDim.x + threadIdx.x;

    // ---- per-b parameters (40 B each of mu, log_sigma2; 8B-aligned -> float2) ----
    float muv[CC], sig[CC];
    const float2* mu2 = reinterpret_cast<const float2*>(mu  + (size_t)b * CC);
    const float2* ls22 = reinterpret_cast<const float2*>(ls2 + (size_t)b * CC);
#pragma unroll
    for (int i = 0; i < CC / 2; ++i) {
        float2 m2 = mu2[i];
        float2 s2 = ls22[i];
        muv[2 * i]     = m2.x;
        muv[2 * i + 1] = m2.y;
        sig[2 * i]     = __expf(0.5f * s2.x);
        sig[2 * i + 1] = __expf(0.5f * s2.y);
    }
    const int yi = y[b];

    // ---- online logsumexp over the T MC samples ----
    float M = -INFINITY, S = 0.0f;
    for (int t = 0; t < TT; ++t) {
        const float2* e2 = reinterpret_cast<const float2*>(
            eps + ((size_t)t * BB + (size_t)b) * CC);
        float l[CC];
#pragma unroll
        for (int i = 0; i < CC / 2; ++i) {
            float2 e = e2[i];
            l[2 * i]     = fmaf(sig[2 * i],     e.x, muv[2 * i]);
            l[2 * i + 1] = fmaf(sig[2 * i + 1], e.y, muv[2 * i + 1]);
        }
        // row max + gather logit[y] via compile-time-unrolled select (no runtime array index)
        float m = -INFINITY;
        float ly = 0.0f;
#pragma unroll
        for (int c = 0; c < CC; ++c) {
            m = fmaxf(m, l[c]);
            ly = (c == yi) ? l[c] : ly;
        }
        float s = 0.0f;
#pragma unroll
        for (int c = 0; c < CC; ++c) s += __expf(l[c] - m);
        const float v = ly - (m + __logf(s));   // logp at class y for this sample

        // branchless online LSE accumulate over t
        const float nm = fmaxf(M, v);
        S = S * __expf(M - nm) + __expf(v - nm);
        M = nm;
    }
    const float picked_no_logT = M + __logf(S);   // = lse[b, y[b]] + log T

    // ---- block reduction: wave shuffle -> LDS -> one atomic per block ----
    float x = picked_no_logT;
#pragma unroll
    for (int off = 32; off > 0; off >>= 1)
        x += __shfl_down(x, off, 64);

    __shared__ float wsum[4];
    const int lane = threadIdx.x & 63;
    const int wid  = threadIdx.x >> 6;
    if (lane == 0) wsum[wid] = x;
    __syncthreads();
    if (threadIdx.x == 0) {
        float bs = wsum[0] + wsum[1] + wsum[2] + wsum[3];
        atomicAdd(out, -bs * (1.0f / (float)BB));
    }
}

extern "C" void kernel_launch(void* const* d_in, const int* in_sizes, int n_in,
                              void* d_out, int out_size, void* d_ws, size_t ws_size,
                              hipStream_t stream) {
    const float* mu  = (const float*)d_in[0];
    const float* ls2 = (const float*)d_in[1];
    const int*   y   = (const int*)d_in[2];
    const float* eps = (const float*)d_in[3];
    float* out = (float*)d_out;

    hipLaunchKernelGGL(init_out_kernel, dim3(1), dim3(1), 0, stream, out);
    hipLaunchKernelGGL(mc_nll_kernel, dim3(BB / 256), dim3(256), 0, stream,
                       mu, ls2, y, eps, out);
}